// Round 1
// baseline (1231.480 us; speedup 1.0000x reference)
//
#include <hip/hip_runtime.h>
#include <math.h>

#define NA 32          // N_AGENTS
#define SD 2048        // STATE_DIM
#define EB 64          // EMBED
#define BT 2048        // B = BS*T
#define NCAT 2240      // 2048 (Ww1) + 64 (Wwf) + 64 (Wb1) + 64 (Wv1)

// ---------------- K1: Y = st @ [Ww1|Wwf|Wb1|Wv1] + bias ----------------
// tile 128(M) x 64(N), Ktile 16, 256 threads, microtile 4m x 8n.
// Each 64-col tile lies entirely inside one weight region (boundaries at
// 2048/2112/2176 are 64-aligned), so per-block region dispatch is uniform.
__global__ __launch_bounds__(256) void k1_gemm(
    const float* __restrict__ st,
    const float* __restrict__ Ww1, const float* __restrict__ bw1,
    const float* __restrict__ Wwf, const float* __restrict__ bwf,
    const float* __restrict__ Wb1, const float* __restrict__ bb1,
    const float* __restrict__ Wv1, const float* __restrict__ bv1,
    float* __restrict__ Y)
{
    const int bx = blockIdx.x;   // 0..34  (n tile of 64)
    const int by = blockIdx.y;   // 0..15  (m tile of 128)
    const float* Bp; const float* bias; int ldb;
    if (bx < 32)       { Bp = Ww1 + bx*64; bias = bw1 + bx*64; ldb = 2048; }
    else if (bx == 32) { Bp = Wwf;         bias = bwf;         ldb = 64; }
    else if (bx == 33) { Bp = Wb1;         bias = bb1;         ldb = 64; }
    else               { Bp = Wv1;         bias = bv1;         ldb = 64; }

    __shared__ float As[16][128];
    __shared__ float Bs[16][64];

    const int t  = threadIdx.x;
    const int tn = t & 7;    // col group: tn*8
    const int tm = t >> 3;   // row group: tm*4 (0..31)
    const int m0 = by * 128;

    float acc[4][8];
    #pragma unroll
    for (int i = 0; i < 4; i++)
        #pragma unroll
        for (int j = 0; j < 8; j++) acc[i][j] = 0.f;

    for (int kt = 0; kt < SD; kt += 16) {
        // stage A tile 128x16 (transposed to [k][m])
        {
            int l = t * 8;
            int m = l >> 4, k = l & 15;     // k in {0,8}
            const float* src = &st[(size_t)(m0 + m) * SD + kt + k];
            float4 v0 = *(const float4*)(src);
            float4 v1 = *(const float4*)(src + 4);
            As[k+0][m] = v0.x; As[k+1][m] = v0.y; As[k+2][m] = v0.z; As[k+3][m] = v0.w;
            As[k+4][m] = v1.x; As[k+5][m] = v1.y; As[k+6][m] = v1.z; As[k+7][m] = v1.w;
        }
        // stage B tile 16x64
        {
            int l = t * 4;
            int k = l >> 6, n = l & 63;
            float4 v = *(const float4*)&Bp[(size_t)(kt + k) * ldb + n];
            *(float4*)&Bs[k][n] = v;
        }
        __syncthreads();
        #pragma unroll
        for (int k = 0; k < 16; k++) {
            float4 a  = *(const float4*)&As[k][tm * 4];
            float4 b0 = *(const float4*)&Bs[k][tn * 8];
            float4 b1 = *(const float4*)&Bs[k][tn * 8 + 4];
            float am[4] = {a.x, a.y, a.z, a.w};
            float bn[8] = {b0.x, b0.y, b0.z, b0.w, b1.x, b1.y, b1.z, b1.w};
            #pragma unroll
            for (int i = 0; i < 4; i++)
                #pragma unroll
                for (int j = 0; j < 8; j++) acc[i][j] += am[i] * bn[j];
        }
        __syncthreads();
    }

    const int c0 = bx * 64 + tn * 8;
    #pragma unroll
    for (int i = 0; i < 4; i++) {
        int row = m0 + tm * 4 + i;
        float* dst = &Y[(size_t)row * NCAT + c0];
        float4 o0, o1;
        o0.x = acc[i][0] + bias[tn*8+0]; o0.y = acc[i][1] + bias[tn*8+1];
        o0.z = acc[i][2] + bias[tn*8+2]; o0.w = acc[i][3] + bias[tn*8+3];
        o1.x = acc[i][4] + bias[tn*8+4]; o1.y = acc[i][5] + bias[tn*8+5];
        o1.z = acc[i][6] + bias[tn*8+6]; o1.w = acc[i][7] + bias[tn*8+7];
        *(float4*)(dst)     = o0;
        *(float4*)(dst + 4) = o1;
    }
}

// ---------------- K3: q1[i][b] for 32 masks x 2048 states ----------------
// block = (mask i, tile of 32 b). P = st_chunk @ W_chunk computed on the fly;
// D = Y - P; epilogue (abs/elu/relu + reductions) fused via LDS.
__global__ __launch_bounds__(256) void k3_q1(
    const float* __restrict__ st, const float* __restrict__ qs,
    const float* __restrict__ Ww1, const float* __restrict__ Wwf,
    const float* __restrict__ Wb1, const float* __restrict__ Wv1,
    const float* __restrict__ Wv2, const float* __restrict__ bv2,
    const float* __restrict__ Y, float* __restrict__ q1)
{
    const int i  = blockIdx.x;        // mask index 0..31
    const int b0 = blockIdx.y * 32;   // state tile base

    __shared__ float s_lds[64][32];    // [k][b]  st chunk, transposed
    __shared__ float qs_lds[32][32];   // [b][a]
    __shared__ float hid_lds[32][64];  // [b][e]  sum_a qs*|D|
    __shared__ float wf_lds[32][64];   // [b][e]  |D_f|
    __shared__ float b1_lds[32][64];   // [b][e]  D_b
    __shared__ float v_lds[32];        // [b]     sum_e relu(D_v)*Wv2

    const int t = threadIdx.x;
    {
        int l = t * 8; int b = l >> 6, k = l & 63;   // 8 consecutive k per thread
        const float* src = &st[(size_t)(b0 + b) * SD + i * 64 + k];
        #pragma unroll
        for (int u = 0; u < 8; u++) s_lds[k + u][b] = src[u];
    }
    {
        int l = t * 4; int b = l >> 5, a = l & 31;
        *(float4*)&qs_lds[b][a] = *(const float4*)&qs[(size_t)(b0 + b) * NA + a];
    }
    for (int l = t; l < 32 * 64; l += 256) ((float*)hid_lds)[l] = 0.f;
    if (t < 32) v_lds[t] = 0.f;
    __syncthreads();

    const int jt = t & 31, bt = t >> 5;   // microtile: 4 b x 8 j
    const int row0 = i * 64;

    // main: the 2048 Ww1 columns, 8 column-tiles of 256
    for (int ct = 0; ct < 8; ct++) {
        const int j0 = ct * 256 + jt * 8;
        float acc[4][8];
        #pragma unroll
        for (int bi = 0; bi < 4; bi++)
            #pragma unroll
            for (int jj = 0; jj < 8; jj++) acc[bi][jj] = 0.f;

        const float* wp = &Ww1[(size_t)row0 * SD + j0];
        #pragma unroll 4
        for (int k = 0; k < 64; k++) {
            float4 w0 = *(const float4*)&wp[(size_t)k * SD];
            float4 w1 = *(const float4*)&wp[(size_t)k * SD + 4];
            float4 s4 = *(const float4*)&s_lds[k][bt * 4];
            float wn[8] = {w0.x, w0.y, w0.z, w0.w, w1.x, w1.y, w1.z, w1.w};
            float sb[4] = {s4.x, s4.y, s4.z, s4.w};
            #pragma unroll
            for (int bi = 0; bi < 4; bi++)
                #pragma unroll
                for (int jj = 0; jj < 8; jj++) acc[bi][jj] += sb[bi] * wn[jj];
        }
        const int a  = ct * 4 + (jt >> 3);
        const int e0 = (jt & 7) * 8;
        #pragma unroll
        for (int bi = 0; bi < 4; bi++) {
            int b = bt * 4 + bi;
            const float* yrow = &Y[(size_t)(b0 + b) * NCAT + j0];
            float4 y0 = *(const float4*)(yrow);
            float4 y1 = *(const float4*)(yrow + 4);
            float yv[8] = {y0.x, y0.y, y0.z, y0.w, y1.x, y1.y, y1.z, y1.w};
            float qv = qs_lds[b][a];
            #pragma unroll
            for (int jj = 0; jj < 8; jj++) {
                float D = yv[jj] - acc[bi][jj];
                atomicAdd(&hid_lds[b][e0 + jj], qv * fabsf(D));
            }
        }
    }

    // tail: 192 columns (wf / b1 / v), one column per thread t<192
    if (t < 192) {
        const float* wptr; int e = t & 63;
        if (t < 64)       wptr = Wwf + t;
        else if (t < 128) wptr = Wb1 + (t - 64);
        else              wptr = Wv1 + (t - 128);
        float acc2[32];
        #pragma unroll
        for (int b = 0; b < 32; b++) acc2[b] = 0.f;
        for (int k = 0; k < 64; k++) {
            float w = wptr[(size_t)(row0 + k) * EB];
            #pragma unroll
            for (int bg = 0; bg < 8; bg++) {
                float4 s4 = *(const float4*)&s_lds[k][bg * 4];
                acc2[bg*4+0] += s4.x * w; acc2[bg*4+1] += s4.y * w;
                acc2[bg*4+2] += s4.z * w; acc2[bg*4+3] += s4.w * w;
            }
        }
        float wv2 = (t >= 128) ? Wv2[t - 128] : 0.f;
        for (int b = 0; b < 32; b++) {
            float D = Y[(size_t)(b0 + b) * NCAT + 2048 + t] - acc2[b];
            if (t < 64)       wf_lds[b][e] = fabsf(D);
            else if (t < 128) b1_lds[b][e] = D;
            else              atomicAdd(&v_lds[b], fmaxf(D, 0.f) * wv2);
        }
    }
    __syncthreads();

    // per-b reduction: hidden = elu(hid+b1); q1 = sum_e hidden*wf + v + bv2
    const int lane = t & 63, w = t >> 6;
    const float bv2v = bv2[0];
    for (int bb = 0; bb < 8; bb++) {
        int b = w * 8 + bb;
        float h = hid_lds[b][lane] + b1_lds[b][lane];
        float hid = h > 0.f ? h : expm1f(h);
        float val = hid * wf_lds[b][lane];
        #pragma unroll
        for (int off = 32; off > 0; off >>= 1) val += __shfl_down(val, off);
        if (lane == 0) q1[(size_t)i * BT + b0 + b] = val + v_lds[b] + bv2v;
    }
}

// ---------------- K4: q_tot, wc, final weighted mix ----------------
__global__ __launch_bounds__(64) void k4_final(
    const float* __restrict__ qs, const float* __restrict__ Y,
    const float* __restrict__ q1, const float* __restrict__ Wv2,
    const float* __restrict__ bv2, float* __restrict__ out)
{
    const int b = blockIdx.x;
    const int e = threadIdx.x;   // 0..63
    const float* yrow = &Y[(size_t)b * NCAT];

    float w1r[32];
    #pragma unroll
    for (int a = 0; a < 32; a++) w1r[a] = fabsf(yrow[a * 64 + e]);
    float wf   = fabsf(yrow[2048 + e]);
    float b1   = yrow[2112 + e];
    float vpre = fmaxf(yrow[2176 + e], 0.f) * Wv2[e];
    const float bv2v = bv2[0];

    __shared__ float qs_s[32];
    __shared__ float qw[32];
    if (e < 32) qs_s[e] = qs[(size_t)b * NA + e];
    __syncthreads();

    // q_tot with plain qs
    float hl = 0.f;
    #pragma unroll
    for (int a = 0; a < 32; a++) hl += qs_s[a] * w1r[a];
    float hid = hl + b1; hid = hid > 0.f ? hid : expm1f(hid);
    float val = hid * wf + vpre;
    #pragma unroll
    for (int off = 32; off > 0; off >>= 1) val += __shfl_down(val, off);
    float q_tot = __shfl(val, 0) + bv2v;

    // wc = normalize(|q_tot - q1|), qw = qs * wc
    if (e < 32) {
        float d = fabsf(q_tot - q1[(size_t)e * BT + b]);
        float ss = d * d;
        #pragma unroll
        for (int off = 16; off > 0; off >>= 1) ss += __shfl_xor(ss, off, 32);
        float nrm = fmaxf(sqrtf(ss), 1e-12f);
        qw[e] = qs_s[e] * (d / nrm);
    }
    __syncthreads();

    float hl2 = 0.f;
    #pragma unroll
    for (int a = 0; a < 32; a++) hl2 += qw[a] * w1r[a];
    float hid2 = hl2 + b1; hid2 = hid2 > 0.f ? hid2 : expm1f(hid2);
    float val2 = hid2 * wf + vpre;
    #pragma unroll
    for (int off = 32; off > 0; off >>= 1) val2 += __shfl_down(val2, off);
    if (e == 0) out[b] = val2 + bv2v;
}

extern "C" void kernel_launch(void* const* d_in, const int* in_sizes, int n_in,
                              void* d_out, int out_size, void* d_ws, size_t ws_size,
                              hipStream_t stream) {
    const float* qs  = (const float*)d_in[0];
    const float* st  = (const float*)d_in[1];
    const float* Ww1 = (const float*)d_in[2];
    const float* bw1 = (const float*)d_in[3];
    const float* Wwf = (const float*)d_in[4];
    const float* bwf = (const float*)d_in[5];
    const float* Wb1 = (const float*)d_in[6];
    const float* bb1 = (const float*)d_in[7];
    const float* Wv1 = (const float*)d_in[8];
    const float* bv1 = (const float*)d_in[9];
    const float* Wv2 = (const float*)d_in[10];
    const float* bv2 = (const float*)d_in[11];
    float* out = (float*)d_out;

    float* Y  = (float*)d_ws;                    // 2048*2240 floats = 18.35 MB
    float* q1 = Y + (size_t)BT * NCAT;           // 32*2048 floats

    k1_gemm<<<dim3(35, 16), 256, 0, stream>>>(st, Ww1, bw1, Wwf, bwf, Wb1, bb1, Wv1, bv1, Y);
    k3_q1 <<<dim3(32, 64), 256, 0, stream>>>(st, qs, Ww1, Wwf, Wb1, Wv1, Wv2, bv2, Y, q1);
    k4_final<<<BT, 64, 0, stream>>>(qs, Y, q1, Wv2, bv2, out);
}

// Round 2
// 730.008 us; speedup vs baseline: 1.6869x; 1.6869x over previous
//
#include <hip/hip_runtime.h>
#include <math.h>

#define NA 32          // N_AGENTS
#define SD 2048        // STATE_DIM
#define EB 64          // EMBED
#define BT 2048        // B = BS*T
#define NCAT 2240      // 2048 (Ww1) + 64 (Wwf) + 64 (Wb1) + 64 (Wv1)

// ---------------- K1: Y = st @ [Ww1|Wwf|Wb1|Wv1] + bias ----------------
__global__ __launch_bounds__(256) void k1_gemm(
    const float* __restrict__ st,
    const float* __restrict__ Ww1, const float* __restrict__ bw1,
    const float* __restrict__ Wwf, const float* __restrict__ bwf,
    const float* __restrict__ Wb1, const float* __restrict__ bb1,
    const float* __restrict__ Wv1, const float* __restrict__ bv1,
    float* __restrict__ Y)
{
    const int bx = blockIdx.x;   // 0..34  (n tile of 64)
    const int by = blockIdx.y;   // 0..15  (m tile of 128)
    const float* Bp; const float* bias; int ldb;
    if (bx < 32)       { Bp = Ww1 + bx*64; bias = bw1 + bx*64; ldb = 2048; }
    else if (bx == 32) { Bp = Wwf;         bias = bwf;         ldb = 64; }
    else if (bx == 33) { Bp = Wb1;         bias = bb1;         ldb = 64; }
    else               { Bp = Wv1;         bias = bv1;         ldb = 64; }

    __shared__ float As[16][128];
    __shared__ float Bs[16][64];

    const int t  = threadIdx.x;
    const int tn = t & 7;    // col group: tn*8
    const int tm = t >> 3;   // row group: tm*4 (0..31)
    const int m0 = by * 128;

    float acc[4][8];
    #pragma unroll
    for (int i = 0; i < 4; i++)
        #pragma unroll
        for (int j = 0; j < 8; j++) acc[i][j] = 0.f;

    for (int kt = 0; kt < SD; kt += 16) {
        {
            int l = t * 8;
            int m = l >> 4, k = l & 15;     // k in {0,8}
            const float* src = &st[(size_t)(m0 + m) * SD + kt + k];
            float4 v0 = *(const float4*)(src);
            float4 v1 = *(const float4*)(src + 4);
            As[k+0][m] = v0.x; As[k+1][m] = v0.y; As[k+2][m] = v0.z; As[k+3][m] = v0.w;
            As[k+4][m] = v1.x; As[k+5][m] = v1.y; As[k+6][m] = v1.z; As[k+7][m] = v1.w;
        }
        {
            int l = t * 4;
            int k = l >> 6, n = l & 63;
            float4 v = *(const float4*)&Bp[(size_t)(kt + k) * ldb + n];
            *(float4*)&Bs[k][n] = v;
        }
        __syncthreads();
        #pragma unroll
        for (int k = 0; k < 16; k++) {
            float4 a  = *(const float4*)&As[k][tm * 4];
            float4 b0 = *(const float4*)&Bs[k][tn * 8];
            float4 b1 = *(const float4*)&Bs[k][tn * 8 + 4];
            float am[4] = {a.x, a.y, a.z, a.w};
            float bn[8] = {b0.x, b0.y, b0.z, b0.w, b1.x, b1.y, b1.z, b1.w};
            #pragma unroll
            for (int i = 0; i < 4; i++)
                #pragma unroll
                for (int j = 0; j < 8; j++) acc[i][j] += am[i] * bn[j];
        }
        __syncthreads();
    }

    const int c0 = bx * 64 + tn * 8;
    #pragma unroll
    for (int i = 0; i < 4; i++) {
        int row = m0 + tm * 4 + i;
        float* dst = &Y[(size_t)row * NCAT + c0];
        float4 o0, o1;
        o0.x = acc[i][0] + bias[tn*8+0]; o0.y = acc[i][1] + bias[tn*8+1];
        o0.z = acc[i][2] + bias[tn*8+2]; o0.w = acc[i][3] + bias[tn*8+3];
        o1.x = acc[i][4] + bias[tn*8+4]; o1.y = acc[i][5] + bias[tn*8+5];
        o1.z = acc[i][6] + bias[tn*8+6]; o1.w = acc[i][7] + bias[tn*8+7];
        *(float4*)(dst)     = o0;
        *(float4*)(dst + 4) = o1;
    }
}

// ---------------- K3: q1[i][b] for 32 masks x 2048 states ----------------
// Atomic-free rework: hid accumulated in registers across the agent loop
// (e-columns per thread are ct-invariant), combined across the 4 lane-groups
// that share (b,e) via two shfl_xor, single plain LDS store. v-path likewise
// via a v_part[b][e] LDS array folded into the final shuffle reduction.
__global__ __launch_bounds__(256) void k3_q1(
    const float* __restrict__ st, const float* __restrict__ qs,
    const float* __restrict__ Ww1, const float* __restrict__ Wwf,
    const float* __restrict__ Wb1, const float* __restrict__ Wv1,
    const float* __restrict__ Wv2, const float* __restrict__ bv2,
    const float* __restrict__ Y, float* __restrict__ q1)
{
    const int i  = blockIdx.x;        // mask index 0..31
    const int b0 = blockIdx.y * 32;   // state tile base

    __shared__ float s_lds[64][32];    // [k][b]  st chunk, transposed
    __shared__ float qs_lds[32][32];   // [b][a]
    __shared__ float hid_lds[32][64];  // [b][e]  sum_a qs*|D|
    __shared__ float wf_lds[32][64];   // [b][e]  |D_f|
    __shared__ float b1_lds[32][64];   // [b][e]  D_b
    __shared__ float v_lds[32][64];    // [b][e]  relu(D_v)*Wv2[e]

    const int t = threadIdx.x;
    {
        int l = t * 8; int b = l >> 6, k = l & 63;   // 8 consecutive k per thread
        const float* src = &st[(size_t)(b0 + b) * SD + i * 64 + k];
        #pragma unroll
        for (int u = 0; u < 8; u++) s_lds[k + u][b] = src[u];
    }
    {
        int l = t * 4; int b = l >> 5, a = l & 31;
        *(float4*)&qs_lds[b][a] = *(const float4*)&qs[(size_t)(b0 + b) * NA + a];
    }
    __syncthreads();

    const int jt = t & 31, bt = t >> 5;   // microtile: 4 b x 8 j
    const int row0 = i * 64;

    float hid_acc[4][8];
    #pragma unroll
    for (int bi = 0; bi < 4; bi++)
        #pragma unroll
        for (int jj = 0; jj < 8; jj++) hid_acc[bi][jj] = 0.f;

    // main: the 2048 Ww1 columns, 8 column-tiles of 256 (one agent per
    // (ct, jt>>3) pair; e-range (jt&7)*8 fixed per thread)
    for (int ct = 0; ct < 8; ct++) {
        const int j0 = ct * 256 + jt * 8;
        float acc[4][8];
        #pragma unroll
        for (int bi = 0; bi < 4; bi++)
            #pragma unroll
            for (int jj = 0; jj < 8; jj++) acc[bi][jj] = 0.f;

        const float* wp = &Ww1[(size_t)row0 * SD + j0];
        #pragma unroll 4
        for (int k = 0; k < 64; k++) {
            float4 w0 = *(const float4*)&wp[(size_t)k * SD];
            float4 w1 = *(const float4*)&wp[(size_t)k * SD + 4];
            float4 s4 = *(const float4*)&s_lds[k][bt * 4];
            float wn[8] = {w0.x, w0.y, w0.z, w0.w, w1.x, w1.y, w1.z, w1.w};
            float sb[4] = {s4.x, s4.y, s4.z, s4.w};
            #pragma unroll
            for (int bi = 0; bi < 4; bi++)
                #pragma unroll
                for (int jj = 0; jj < 8; jj++) acc[bi][jj] += sb[bi] * wn[jj];
        }
        const int a = ct * 4 + (jt >> 3);
        #pragma unroll
        for (int bi = 0; bi < 4; bi++) {
            int b = bt * 4 + bi;
            const float* yrow = &Y[(size_t)(b0 + b) * NCAT + j0];
            float4 y0 = *(const float4*)(yrow);
            float4 y1 = *(const float4*)(yrow + 4);
            float yv[8] = {y0.x, y0.y, y0.z, y0.w, y1.x, y1.y, y1.z, y1.w};
            float qv = qs_lds[b][a];
            #pragma unroll
            for (int jj = 0; jj < 8; jj++) {
                float D = yv[jj] - acc[bi][jj];
                hid_acc[bi][jj] += qv * fabsf(D);
            }
        }
    }

    // combine the 4 lane-groups (jt>>3 = 0..3, lane offsets 8/16/24) that
    // share (b, e); butterfly keeps everything in-wave.
    #pragma unroll
    for (int bi = 0; bi < 4; bi++)
        #pragma unroll
        for (int jj = 0; jj < 8; jj++) {
            float v = hid_acc[bi][jj];
            v += __shfl_xor(v, 8);
            v += __shfl_xor(v, 16);
            hid_acc[bi][jj] = v;
        }
    if ((jt >> 3) == 0) {
        const int e0 = jt * 8;
        #pragma unroll
        for (int bi = 0; bi < 4; bi++) {
            int b = bt * 4 + bi;
            float4 h0, h1;
            h0.x = hid_acc[bi][0]; h0.y = hid_acc[bi][1];
            h0.z = hid_acc[bi][2]; h0.w = hid_acc[bi][3];
            h1.x = hid_acc[bi][4]; h1.y = hid_acc[bi][5];
            h1.z = hid_acc[bi][6]; h1.w = hid_acc[bi][7];
            *(float4*)&hid_lds[b][e0]     = h0;
            *(float4*)&hid_lds[b][e0 + 4] = h1;
        }
    }

    // tail: 192 columns (wf / b1 / v), one column per thread t<192
    if (t < 192) {
        const float* wptr; int e = t & 63;
        if (t < 64)       wptr = Wwf + t;
        else if (t < 128) wptr = Wb1 + (t - 64);
        else              wptr = Wv1 + (t - 128);
        float acc2[32];
        #pragma unroll
        for (int b = 0; b < 32; b++) acc2[b] = 0.f;
        for (int k = 0; k < 64; k++) {
            float w = wptr[(size_t)(row0 + k) * EB];
            #pragma unroll
            for (int bg = 0; bg < 8; bg++) {
                float4 s4 = *(const float4*)&s_lds[k][bg * 4];
                acc2[bg*4+0] += s4.x * w; acc2[bg*4+1] += s4.y * w;
                acc2[bg*4+2] += s4.z * w; acc2[bg*4+3] += s4.w * w;
            }
        }
        float wv2 = (t >= 128) ? Wv2[t - 128] : 0.f;
        for (int b = 0; b < 32; b++) {
            float D = Y[(size_t)(b0 + b) * NCAT + 2048 + t] - acc2[b];
            if (t < 64)       wf_lds[b][e] = fabsf(D);
            else if (t < 128) b1_lds[b][e] = D;
            else              v_lds[b][e]  = fmaxf(D, 0.f) * wv2;
        }
    }
    __syncthreads();

    // per-b reduction: hidden = elu(hid+b1); q1 = sum_e (hidden*wf + v) + bv2
    const int lane = t & 63, w = t >> 6;
    const float bv2v = bv2[0];
    for (int bb = 0; bb < 8; bb++) {
        int b = w * 8 + bb;
        float h = hid_lds[b][lane] + b1_lds[b][lane];
        float hid = h > 0.f ? h : expm1f(h);
        float val = hid * wf_lds[b][lane] + v_lds[b][lane];
        #pragma unroll
        for (int off = 32; off > 0; off >>= 1) val += __shfl_down(val, off);
        if (lane == 0) q1[(size_t)i * BT + b0 + b] = val + bv2v;
    }
}

// ---------------- K4: q_tot, wc, final weighted mix ----------------
__global__ __launch_bounds__(64) void k4_final(
    const float* __restrict__ qs, const float* __restrict__ Y,
    const float* __restrict__ q1, const float* __restrict__ Wv2,
    const float* __restrict__ bv2, float* __restrict__ out)
{
    const int b = blockIdx.x;
    const int e = threadIdx.x;   // 0..63
    const float* yrow = &Y[(size_t)b * NCAT];

    float w1r[32];
    #pragma unroll
    for (int a = 0; a < 32; a++) w1r[a] = fabsf(yrow[a * 64 + e]);
    float wf   = fabsf(yrow[2048 + e]);
    float b1   = yrow[2112 + e];
    float vpre = fmaxf(yrow[2176 + e], 0.f) * Wv2[e];
    const float bv2v = bv2[0];

    __shared__ float qs_s[32];
    __shared__ float qw[32];
    if (e < 32) qs_s[e] = qs[(size_t)b * NA + e];
    __syncthreads();

    float hl = 0.f;
    #pragma unroll
    for (int a = 0; a < 32; a++) hl += qs_s[a] * w1r[a];
    float hid = hl + b1; hid = hid > 0.f ? hid : expm1f(hid);
    float val = hid * wf + vpre;
    #pragma unroll
    for (int off = 32; off > 0; off >>= 1) val += __shfl_down(val, off);
    float q_tot = __shfl(val, 0) + bv2v;

    if (e < 32) {
        float d = fabsf(q_tot - q1[(size_t)e * BT + b]);
        float ss = d * d;
        #pragma unroll
        for (int off = 16; off > 0; off >>= 1) ss += __shfl_xor(ss, off, 32);
        float nrm = fmaxf(sqrtf(ss), 1e-12f);
        qw[e] = qs_s[e] * (d / nrm);
    }
    __syncthreads();

    float hl2 = 0.f;
    #pragma unroll
    for (int a = 0; a < 32; a++) hl2 += qw[a] * w1r[a];
    float hid2 = hl2 + b1; hid2 = hid2 > 0.f ? hid2 : expm1f(hid2);
    float val2 = hid2 * wf + vpre;
    #pragma unroll
    for (int off = 32; off > 0; off >>= 1) val2 += __shfl_down(val2, off);
    if (e == 0) out[b] = val2 + bv2v;
}

extern "C" void kernel_launch(void* const* d_in, const int* in_sizes, int n_in,
                              void* d_out, int out_size, void* d_ws, size_t ws_size,
                              hipStream_t stream) {
    const float* qs  = (const float*)d_in[0];
    const float* st  = (const float*)d_in[1];
    const float* Ww1 = (const float*)d_in[2];
    const float* bw1 = (const float*)d_in[3];
    const float* Wwf = (const float*)d_in[4];
    const float* bwf = (const float*)d_in[5];
    const float* Wb1 = (const float*)d_in[6];
    const float* bb1 = (const float*)d_in[7];
    const float* Wv1 = (const float*)d_in[8];
    const float* bv1 = (const float*)d_in[9];
    const float* Wv2 = (const float*)d_in[10];
    const float* bv2 = (const float*)d_in[11];
    float* out = (float*)d_out;

    float* Y  = (float*)d_ws;                    // 2048*2240 floats = 18.35 MB
    float* q1 = Y + (size_t)BT * NCAT;           // 32*2048 floats

    k1_gemm<<<dim3(35, 16), 256, 0, stream>>>(st, Ww1, bw1, Wwf, bwf, Wb1, bb1, Wv1, bv1, Y);
    k3_q1 <<<dim3(32, 64), 256, 0, stream>>>(st, qs, Ww1, Wwf, Wb1, Wv1, Wv2, bv2, Y, q1);
    k4_final<<<BT, 64, 0, stream>>>(qs, Y, q1, Wv2, bv2, out);
}

// Round 3
// 324.512 us; speedup vs baseline: 3.7949x; 2.2496x over previous
//
#include <hip/hip_runtime.h>
#include <math.h>
#include <stdint.h>

#define NA 32          // N_AGENTS
#define SD 2048        // STATE_DIM
#define EB 64          // EMBED
#define BT 2048        // B = BS*T
#define NCAT 2240      // 2048 (Ww1) + 64 (Wwf) + 64 (Wb1) + 64 (Wv1)
#define NPAD 2304      // padded to 18 tiles of 128
#define YS   2304      // Y row stride (fp32)

typedef float floatx4 __attribute__((ext_vector_type(4)));
typedef short bf16x8  __attribute__((ext_vector_type(8)));

__device__ __forceinline__ unsigned short f2bf(float f) {
    union { float f; uint32_t u; } v; v.f = f;
    uint32_t r = v.u + 0x7FFFu + ((v.u >> 16) & 1u);
    return (unsigned short)(r >> 16);
}

__device__ __forceinline__ void gload_lds16(const void* g, void* l) {
    __builtin_amdgcn_global_load_lds(
        (const __attribute__((address_space(1))) uint32_t*)g,
        (__attribute__((address_space(3))) uint32_t*)l, 16, 0, 0);
}

// ---------------- K0a: st -> bf16 row-major ----------------
__global__ __launch_bounds__(256) void k0_st2bf(const float* __restrict__ st,
                                                unsigned short* __restrict__ stb) {
    int idx = (blockIdx.x * 256 + threadIdx.x) * 4;
    float4 v = *(const float4*)(st + idx);
    ushort4 o;
    o.x = f2bf(v.x); o.y = f2bf(v.y); o.z = f2bf(v.z); o.w = f2bf(v.w);
    *(ushort4*)(stb + idx) = o;
}

// ---------------- K0b: Wt[n][k] bf16 (transposed concat, padded) ----------
__global__ __launch_bounds__(256) void k0_wt(const float* __restrict__ Ww1,
                                             const float* __restrict__ Wwf,
                                             const float* __restrict__ Wb1,
                                             const float* __restrict__ Wv1,
                                             unsigned short* __restrict__ Wtb) {
    __shared__ float tile[32][33];
    const int n0 = blockIdx.x * 32;   // 72 tiles (incl. pad)
    const int k0 = blockIdx.y * 32;   // 64 tiles
    const float* src; int ld = 64, nb = 0;
    if (n0 < 2048)      { src = Ww1; ld = 2048; nb = n0; }
    else if (n0 < 2112) { src = Wwf; nb = n0 - 2048; }
    else if (n0 < 2176) { src = Wb1; nb = n0 - 2112; }
    else if (n0 < 2240) { src = Wv1; nb = n0 - 2176; }
    else                { src = nullptr; }
    const int t = threadIdx.x;
    {
        int nl = t & 31, kl0 = t >> 5;
        #pragma unroll
        for (int r = 0; r < 4; r++) {
            int kl = kl0 + r * 8;
            tile[kl][nl] = src ? src[(size_t)(k0 + kl) * ld + nb + nl] : 0.f;
        }
    }
    __syncthreads();
    {
        int kl = t & 31, nl0 = t >> 5;
        #pragma unroll
        for (int r = 0; r < 4; r++) {
            int nl = nl0 + r * 8;
            Wtb[(size_t)(n0 + nl) * SD + k0 + kl] = f2bf(tile[kl][nl]);
        }
    }
}

// ---------------- K0c: concat bias (padded) ----------------
__global__ void k0_bias(const float* __restrict__ bw1, const float* __restrict__ bwf,
                        const float* __restrict__ bb1, const float* __restrict__ bv1,
                        float* __restrict__ bcat) {
    int n = blockIdx.x * 256 + threadIdx.x;
    if (n >= NPAD) return;
    float v = 0.f;
    if (n < 2048)      v = bw1[n];
    else if (n < 2112) v = bwf[n - 2048];
    else if (n < 2176) v = bb1[n - 2112];
    else if (n < 2240) v = bv1[n - 2176];
    bcat[n] = v;
}

// ---------------- K1: Y = st @ Wcat + bias  (bf16 MFMA) ----------------
// tile M64 x N128, 4 waves (2m x 2n), K-step 32, global_load_lds staging.
__global__ __launch_bounds__(256) void k1_gemm(const unsigned short* __restrict__ stb,
                                               const unsigned short* __restrict__ Wtb,
                                               const float* __restrict__ bcat,
                                               float* __restrict__ Y)
{
    __shared__ short As[4 * 64 * 8];    // [kg][m 0..63][8k]
    __shared__ short Bs[4 * 128 * 8];   // [kg][n 0..127][8k]
    const int t = threadIdx.x;
    const int n0 = blockIdx.x * 128;
    const int m0 = blockIdx.y * 64;
    const int wid = t >> 6, lane = t & 63;
    const int wm = wid & 1, wn = wid >> 1;
    const int quad = lane >> 4, l16 = lane & 15;

    floatx4 acc[2][4];
    #pragma unroll
    for (int i = 0; i < 2; i++)
        #pragma unroll
        for (int j = 0; j < 4; j++) acc[i][j] = (floatx4)0.f;

    const int ca_kg = t >> 6, ca_m = t & 63;      // A chunk id = t
    for (int kt = 0; kt < SD; kt += 32) {
        gload_lds16(stb + (size_t)(m0 + ca_m) * SD + kt + ca_kg * 8, (char*)As + t * 16);
        {
            int c = t;
            gload_lds16(Wtb + (size_t)(n0 + (c & 127)) * SD + kt + (c >> 7) * 8, (char*)Bs + c * 16);
            c = t + 256;
            gload_lds16(Wtb + (size_t)(n0 + (c & 127)) * SD + kt + (c >> 7) * 8, (char*)Bs + c * 16);
        }
        __syncthreads();
        bf16x8 a[2], b[4];
        #pragma unroll
        for (int mf = 0; mf < 2; mf++)
            a[mf] = *(const bf16x8*)(As + (quad * 64 + wm * 32 + mf * 16 + l16) * 8);
        #pragma unroll
        for (int nf = 0; nf < 4; nf++)
            b[nf] = *(const bf16x8*)(Bs + (quad * 128 + wn * 64 + nf * 16 + l16) * 8);
        #pragma unroll
        for (int mf = 0; mf < 2; mf++)
            #pragma unroll
            for (int nf = 0; nf < 4; nf++)
                acc[mf][nf] = __builtin_amdgcn_mfma_f32_16x16x32_bf16(a[mf], b[nf], acc[mf][nf], 0, 0, 0);
        __syncthreads();
    }

    #pragma unroll
    for (int mf = 0; mf < 2; mf++)
        #pragma unroll
        for (int nf = 0; nf < 4; nf++) {
            int col = n0 + wn * 64 + nf * 16 + l16;
            float bias = bcat[col];
            #pragma unroll
            for (int r = 0; r < 4; r++) {
                int row = m0 + wm * 32 + mf * 16 + quad * 4 + r;
                Y[(size_t)row * YS + col] = acc[mf][nf][r] + bias;
            }
        }
}

// ---------------- K3: q1[i][b]  (bf16 MFMA, single-wave blocks) ----------
// block = (mask i, 16-row b tile), 64 threads. C-init = -Y so MFMA gives
// R = P - Y; |D|=|R|, D=-R. hid/wf/b1/v all register-resident.
__global__ __launch_bounds__(64) void k3_q1(
    const unsigned short* __restrict__ stb, const float* __restrict__ qs,
    const unsigned short* __restrict__ Wtb, const float* __restrict__ Wv2,
    const float* __restrict__ bv2, const float* __restrict__ Y,
    float* __restrict__ q1)
{
    const int i  = blockIdx.x;        // mask 0..31
    const int b0 = blockIdx.y * 16;   // b tile
    __shared__ short sA[8 * 16 * 8];  // [kgg 0..7][m 0..15][8k]
    __shared__ float qs_s[16][33];

    const int t = threadIdx.x;        // == lane (single wave)
    const int quad = t >> 4, l16 = t & 15;

    {
        int c = t;
        gload_lds16(stb + (size_t)(b0 + (c & 15)) * SD + i * 64 + (c >> 4) * 8, (char*)sA + c * 16);
        c = t + 64;
        gload_lds16(stb + (size_t)(b0 + (c & 15)) * SD + i * 64 + (c >> 4) * 8, (char*)sA + c * 16);
    }
    {
        int b = t >> 2, a0 = (t & 3) * 8;
        const float* src = qs + (size_t)(b0 + b) * NA + a0;
        #pragma unroll
        for (int u = 0; u < 8; u++) qs_s[b][a0 + u] = src[u];
    }
    __syncthreads();

    bf16x8 A0 = *(const bf16x8*)(sA + ((0 * 4 + quad) * 16 + l16) * 8);
    bf16x8 A1 = *(const bf16x8*)(sA + ((1 * 4 + quad) * 16 + l16) * 8);

    floatx4 hid[4], wff[4], b1f[4], vacc = (floatx4)0.f;
    #pragma unroll
    for (int nf = 0; nf < 4; nf++) hid[nf] = (floatx4)0.f;

    const float* Yb = Y + (size_t)b0 * YS;

    for (int it = 0; it < 32; it++) {             // agent a = it
        const int j0 = it * 64;
        floatx4 acc[4];
        #pragma unroll
        for (int nf = 0; nf < 4; nf++) {
            const float* yp = Yb + j0 + nf * 16 + l16;
            floatx4 c;
            #pragma unroll
            for (int r = 0; r < 4; r++) c[r] = -yp[(size_t)(quad * 4 + r) * YS];
            acc[nf] = c;
        }
        #pragma unroll
        for (int nf = 0; nf < 4; nf++) {
            const unsigned short* wp = Wtb + (size_t)(j0 + nf * 16 + l16) * SD + i * 64 + quad * 8;
            bf16x8 bb0 = *(const bf16x8*)(wp);
            bf16x8 bb1 = *(const bf16x8*)(wp + 32);
            acc[nf] = __builtin_amdgcn_mfma_f32_16x16x32_bf16(A0, bb0, acc[nf], 0, 0, 0);
            acc[nf] = __builtin_amdgcn_mfma_f32_16x16x32_bf16(A1, bb1, acc[nf], 0, 0, 0);
        }
        float qv[4];
        #pragma unroll
        for (int r = 0; r < 4; r++) qv[r] = qs_s[quad * 4 + r][it];
        #pragma unroll
        for (int nf = 0; nf < 4; nf++)
            #pragma unroll
            for (int r = 0; r < 4; r++)
                hid[nf][r] += qv[r] * fabsf(acc[nf][r]);
    }

    // tail: cols 2048..2239 (wf | b1 | v), 12 n-frags
    #pragma unroll
    for (int nft = 0; nft < 12; nft++) {
        const int c0 = 2048 + nft * 16;
        const float* yp = Yb + c0 + l16;
        floatx4 c;
        #pragma unroll
        for (int r = 0; r < 4; r++) c[r] = -yp[(size_t)(quad * 4 + r) * YS];
        const unsigned short* wp = Wtb + (size_t)(c0 + l16) * SD + i * 64 + quad * 8;
        bf16x8 bb0 = *(const bf16x8*)(wp);
        bf16x8 bb1 = *(const bf16x8*)(wp + 32);
        c = __builtin_amdgcn_mfma_f32_16x16x32_bf16(A0, bb0, c, 0, 0, 0);
        c = __builtin_amdgcn_mfma_f32_16x16x32_bf16(A1, bb1, c, 0, 0, 0);
        if (nft < 4) {
            #pragma unroll
            for (int r = 0; r < 4; r++) wff[nft][r] = fabsf(c[r]);
        } else if (nft < 8) {
            #pragma unroll
            for (int r = 0; r < 4; r++) b1f[nft - 4][r] = -c[r];
        } else {
            float wv2 = Wv2[(nft - 8) * 16 + l16];
            #pragma unroll
            for (int r = 0; r < 4; r++) vacc[r] += fmaxf(-c[r], 0.f) * wv2;
        }
    }

    const float bv2v = bv2[0];
    #pragma unroll
    for (int r = 0; r < 4; r++) {
        float s = vacc[r];
        #pragma unroll
        for (int nf = 0; nf < 4; nf++) {
            float h = hid[nf][r] + b1f[nf][r];
            h = h > 0.f ? h : expm1f(h);
            s += h * wff[nf][r];
        }
        s += __shfl_xor(s, 1); s += __shfl_xor(s, 2);
        s += __shfl_xor(s, 4); s += __shfl_xor(s, 8);
        if (l16 == 0) q1[(size_t)i * BT + b0 + quad * 4 + r] = s + bv2v;
    }
}

// ---------------- K4: q_tot, wc, final weighted mix ----------------
__global__ __launch_bounds__(64) void k4_final(
    const float* __restrict__ qs, const float* __restrict__ Y,
    const float* __restrict__ q1, const float* __restrict__ Wv2,
    const float* __restrict__ bv2, float* __restrict__ out)
{
    const int b = blockIdx.x;
    const int e = threadIdx.x;   // 0..63
    const float* yrow = &Y[(size_t)b * YS];

    float w1r[32];
    #pragma unroll
    for (int a = 0; a < 32; a++) w1r[a] = fabsf(yrow[a * 64 + e]);
    float wf   = fabsf(yrow[2048 + e]);
    float b1   = yrow[2112 + e];
    float vpre = fmaxf(yrow[2176 + e], 0.f) * Wv2[e];
    const float bv2v = bv2[0];

    __shared__ float qs_s[32];
    __shared__ float qw[32];
    if (e < 32) qs_s[e] = qs[(size_t)b * NA + e];
    __syncthreads();

    float hl = 0.f;
    #pragma unroll
    for (int a = 0; a < 32; a++) hl += qs_s[a] * w1r[a];
    float hid = hl + b1; hid = hid > 0.f ? hid : expm1f(hid);
    float val = hid * wf + vpre;
    #pragma unroll
    for (int off = 32; off > 0; off >>= 1) val += __shfl_down(val, off);
    float q_tot = __shfl(val, 0) + bv2v;

    if (e < 32) {
        float d = fabsf(q_tot - q1[(size_t)e * BT + b]);
        float ss = d * d;
        #pragma unroll
        for (int off = 16; off > 0; off >>= 1) ss += __shfl_xor(ss, off, 32);
        float nrm = fmaxf(sqrtf(ss), 1e-12f);
        qw[e] = qs_s[e] * (d / nrm);
    }
    __syncthreads();

    float hl2 = 0.f;
    #pragma unroll
    for (int a = 0; a < 32; a++) hl2 += qw[a] * w1r[a];
    float hid2 = hl2 + b1; hid2 = hid2 > 0.f ? hid2 : expm1f(hid2);
    float val2 = hid2 * wf + vpre;
    #pragma unroll
    for (int off = 32; off > 0; off >>= 1) val2 += __shfl_down(val2, off);
    if (e == 0) out[b] = val2 + bv2v;
}

extern "C" void kernel_launch(void* const* d_in, const int* in_sizes, int n_in,
                              void* d_out, int out_size, void* d_ws, size_t ws_size,
                              hipStream_t stream) {
    const float* qs  = (const float*)d_in[0];
    const float* st  = (const float*)d_in[1];
    const float* Ww1 = (const float*)d_in[2];
    const float* bw1 = (const float*)d_in[3];
    const float* Wwf = (const float*)d_in[4];
    const float* bwf = (const float*)d_in[5];
    const float* Wb1 = (const float*)d_in[6];
    const float* bb1 = (const float*)d_in[7];
    const float* Wv1 = (const float*)d_in[8];
    const float* bv1 = (const float*)d_in[9];
    const float* Wv2 = (const float*)d_in[10];
    const float* bv2 = (const float*)d_in[11];
    float* out = (float*)d_out;

    // workspace layout (≈37 MB)
    float* Y            = (float*)d_ws;                          // 2048*2304 f32
    unsigned short* stb = (unsigned short*)(Y + (size_t)BT * YS);// 2048*2048 bf16
    unsigned short* Wtb = stb + (size_t)SD * SD;                 // 2304*2048 bf16
    float* bcat         = (float*)(Wtb + (size_t)NPAD * SD);     // 2304 f32
    float* q1v          = bcat + NPAD;                           // 32*2048 f32

    k0_st2bf<<<(SD * SD / 4 + 255) / 256, 256, 0, stream>>>(st, stb);
    k0_wt  <<<dim3(NPAD / 32, SD / 32), 256, 0, stream>>>(Ww1, Wwf, Wb1, Wv1, Wtb);
    k0_bias<<<(NPAD + 255) / 256, 256, 0, stream>>>(bw1, bwf, bb1, bv1, bcat);

    k1_gemm<<<dim3(NPAD / 128, BT / 64), 256, 0, stream>>>(stb, Wtb, bcat, Y);
    k3_q1  <<<dim3(NA, BT / 16), 64, 0, stream>>>(stb, qs, Wtb, Wv2, bv2, Y, q1v);
    k4_final<<<BT, 64, 0, stream>>>(qs, Y, q1v, Wv2, bv2, out);
}